// Round 2
// baseline (813.889 us; speedup 1.0000x reference)
//
#include <hip/hip_runtime.h>

typedef float f32x4 __attribute__((ext_vector_type(4)));
typedef __bf16 bf16x8 __attribute__((ext_vector_type(8)));

struct U8 { unsigned short s[8]; };
static_assert(sizeof(bf16x8) == 16, "bf16x8 must be 16B");

#define NB 4096
#define NT 64
#define BTF (NB * NT * 64)   // 16777216

__device__ __forceinline__ unsigned short f2bf(float x) {
  unsigned int u = __builtin_bit_cast(unsigned int, x);
  u += 0x7fffu + ((u >> 16) & 1u);       // round-to-nearest-even
  return (unsigned short)(u >> 16);
}

__device__ __forceinline__ f32x4 mfma16(bf16x8 a, bf16x8 b, f32x4 c) {
  return __builtin_amdgcn_mfma_f32_16x16x32_bf16(a, b, c, 0, 0, 0);
}

__device__ __forceinline__ bf16x8 cvt8(f32x4 a, f32x4 b) {
  U8 u;
#pragma unroll
  for (int j = 0; j < 4; ++j) { u.s[j] = f2bf(a[j]); u.s[4 + j] = f2bf(b[j]); }
  return __builtin_bit_cast(bf16x8, u);
}

__device__ __forceinline__ bf16x8 loadW8(const float* __restrict__ row, int k0) {
  f32x4 a = *(const f32x4*)(row + k0);
  f32x4 b = *(const f32x4*)(row + k0 + 4);
  return cvt8(a, b);
}

__device__ __forceinline__ bf16x8 loadW8zd(const float* __restrict__ row, int k0, int col) {
  f32x4 a = *(const f32x4*)(row + k0);
  f32x4 b = *(const f32x4*)(row + k0 + 4);
  U8 u;
#pragma unroll
  for (int j = 0; j < 4; ++j) {
    u.s[j]     = (k0 + j     == col) ? (unsigned short)0 : f2bf(a[j]);
    u.s[4 + j] = (k0 + 4 + j == col) ? (unsigned short)0 : f2bf(b[j]);
  }
  return __builtin_bit_cast(bf16x8, u);
}

__device__ __forceinline__ float sigm(float x) { return 1.f / (1.f + __expf(-x)); }
__device__ __forceinline__ float tanh_fast(float x) { return 1.f - 2.f / (__expf(2.f * x) + 1.f); }

__global__ __launch_bounds__(512, 2) void rits_main_kernel(
    const float* __restrict__ values, const float* __restrict__ masks,
    const float* __restrict__ deltas,
    const float* __restrict__ W_dh, const float* __restrict__ b_dh,
    const float* __restrict__ W_dx, const float* __restrict__ b_dx,
    const float* __restrict__ W_hist, const float* __restrict__ b_hist,
    const float* __restrict__ W_feat, const float* __restrict__ b_feat,
    const float* __restrict__ W_comb, const float* __restrict__ b_comb,
    const float* __restrict__ W_ih, const float* __restrict__ b_ih,
    const float* __restrict__ W_hh, const float* __restrict__ b_hh,
    float* __restrict__ out_imp, float* __restrict__ out_est,
    float* __restrict__ out_h, float* __restrict__ loss_ws) {
  const int tid = threadIdx.x;
  const int w = tid >> 6;          // wave 0..7
  const int l = tid & 63;          // lane
  const int rA = l & 15;           // MFMA A-row / C-col index
  const int kg = l >> 4;           // k-group 0..3
  const int wg = blockIdx.x;
  const int b0 = wg * 16;
  const int colh = w * 16 + rA;          // 0..127 (h-dim column this lane owns)
  const int colw = (w & 3) * 16 + rA;    // 0..63  (f-dim column for low/high wave groups)

  __shared__ unsigned short sHb[2][16][136];   // decayed-h bf16, double-buffered
  __shared__ unsigned short sXcb[16][72];      // x_c bf16
  __shared__ unsigned short sCcb[16][72];      // c_c bf16
  __shared__ float sAl[16][68];                // alpha f32
  __shared__ float sWdxB[128];                 // [0..63]=diag(W_dx), [64..127]=b_dx
  __shared__ float sLoss[4][4];

  // ---------------- one-time init ----------------
  if (tid < 64)       sWdxB[tid] = W_dx[tid * 65];
  else if (tid < 128) sWdxB[tid] = b_dx[tid - 64];

  // zero sHb buffer 0 (h starts at 0; gamma*0 = 0)
#pragma unroll
  for (int i = 0; i < 4; ++i) sHb[0][kg * 4 + i][colh] = 0;

  // gate weights: wave w owns gate-tiles {w, 8+w, 16+w, 24+w} -> i,f,g,o for col 16w+rA
  bf16x8 wgf[4][8];
#pragma unroll
  for (int g = 0; g < 4; ++g) {
    int col = g * 128 + colh;
#pragma unroll
    for (int kk = 0; kk < 4; ++kk) wgf[g][kk] = loadW8(W_ih + (size_t)col * 128, kk * 32 + kg * 8);
#pragma unroll
    for (int kk = 0; kk < 4; ++kk) wgf[g][4 + kk] = loadW8(W_hh + (size_t)col * 128, kk * 32 + kg * 8);
  }
  bf16x8 wdhf[2];
#pragma unroll
  for (int kk = 0; kk < 2; ++kk) wdhf[kk] = loadW8(W_dh + (size_t)colh * 64, kk * 32 + kg * 8);

  // wsm: w<4 -> W_hist (K=128); w>=4 -> W_comb (K=128). wfeat: w<4 only (K=64, zero diag)
  bf16x8 wsm[4], wfeat[2];
  if (w < 4) {
#pragma unroll
    for (int kk = 0; kk < 4; ++kk) wsm[kk] = loadW8(W_hist + (size_t)colw * 128, kk * 32 + kg * 8);
#pragma unroll
    for (int kk = 0; kk < 2; ++kk) wfeat[kk] = loadW8zd(W_feat + (size_t)colw * 64, kk * 32 + kg * 8, colw);
  } else {
#pragma unroll
    for (int kk = 0; kk < 4; ++kk) wsm[kk] = loadW8(W_comb + (size_t)colw * 128, kk * 32 + kg * 8);
#pragma unroll
    for (int kk = 0; kk < 2; ++kk) { U8 z = {}; wfeat[kk] = __builtin_bit_cast(bf16x8, z); }
  }

  // biases in registers
  const float bdh = b_dh[colh];
  const float bhist = (w < 4) ? b_hist[colw] : 0.f;
  const float bfeat = (w < 4) ? b_feat[colw] : 0.f;
  const float bcomb = (w >= 4) ? b_comb[colw] : 0.f;
  float bg[4];
#pragma unroll
  for (int g = 0; g < 4; ++g) bg[g] = b_ih[g * 128 + colh] + b_hh[g * 128 + colh];

  f32x4 h_reg = {0.f, 0.f, 0.f, 0.f};
  f32x4 c_reg = {0.f, 0.f, 0.f, 0.f};

  __syncthreads();   // sWdxB visible

  // ---------------- initial (t=0) activation loads ----------------
  bf16x8 mfrag[2], gx[2];
  float xr[4], mr[4];
  {
    const float* mb = masks + (size_t)(b0 + rA) * 4096 + kg * 8;
    f32x4 m0a = *(const f32x4*)mb,        m0b = *(const f32x4*)(mb + 4);
    f32x4 m1a = *(const f32x4*)(mb + 32), m1b = *(const f32x4*)(mb + 36);
    mfrag[0] = cvt8(m0a, m0b);
    mfrag[1] = cvt8(m1a, m1b);
    const float* db = deltas + (size_t)(b0 + rA) * 4096 + kg * 8;
    f32x4 d0a = *(const f32x4*)db,        d0b = *(const f32x4*)(db + 4);
    f32x4 d1a = *(const f32x4*)(db + 32), d1b = *(const f32x4*)(db + 36);
    if (w >= 4) {
      f32x4 wx0 = *(const f32x4*)&sWdxB[kg * 8],      wx0b = *(const f32x4*)&sWdxB[kg * 8 + 4];
      f32x4 bx0 = *(const f32x4*)&sWdxB[64 + kg * 8], bx0b = *(const f32x4*)&sWdxB[64 + kg * 8 + 4];
      f32x4 wx1 = *(const f32x4*)&sWdxB[32 + kg * 8],      wx1b = *(const f32x4*)&sWdxB[32 + kg * 8 + 4];
      f32x4 bx1 = *(const f32x4*)&sWdxB[96 + kg * 8], bx1b = *(const f32x4*)&sWdxB[96 + kg * 8 + 4];
      U8 u0, u1;
#pragma unroll
      for (int j = 0; j < 4; ++j) {
        u0.s[j]     = f2bf(__expf(-fmaxf(d0a[j] * wx0[j]  + bx0[j], 0.f)));
        u0.s[4 + j] = f2bf(__expf(-fmaxf(d0b[j] * wx0b[j] + bx0b[j], 0.f)));
        u1.s[j]     = f2bf(__expf(-fmaxf(d1a[j] * wx1[j]  + bx1[j], 0.f)));
        u1.s[4 + j] = f2bf(__expf(-fmaxf(d1b[j] * wx1b[j] + bx1b[j], 0.f)));
      }
      gx[0] = __builtin_bit_cast(bf16x8, u0);
      gx[1] = __builtin_bit_cast(bf16x8, u1);
    } else {
      U8 z = {};
      gx[0] = gx[1] = __builtin_bit_cast(bf16x8, z);
    }
    if (w < 4) {
#pragma unroll
      for (int i = 0; i < 4; ++i) {
        size_t a = (size_t)(b0 + kg * 4 + i) * 4096 + colw;
        xr[i] = values[a];
        mr[i] = masks[a];
      }
    } else {
#pragma unroll
      for (int i = 0; i < 4; ++i) { xr[i] = 0.f; mr[i] = 0.f; }
    }
  }
  bf16x8 dfrag[2];
  { U8 z = {}; dfrag[0] = dfrag[1] = __builtin_bit_cast(bf16x8, z); }
  __syncthreads();

  // ---------------- time loop: 3 barriers per step ----------------
  for (int t = 0; t < NT; ++t) {
    const int p = t & 1;
    const int tn = (t + 1 < NT) ? (t + 1) : (NT - 1);

    // issue next-step d loads (per-wave redundant; L1/L2-hot)
    const float* db = deltas + (size_t)(b0 + rA) * 4096 + tn * 64 + kg * 8;
    f32x4 d0a = *(const f32x4*)db,        d0b = *(const f32x4*)(db + 4);
    f32x4 d1a = *(const f32x4*)(db + 32), d1b = *(const f32x4*)(db + 36);

    // ---- phase B ----
    float xh[4];
    if (w < 4) {
      f32x4 axh = {0.f, 0.f, 0.f, 0.f};
#pragma unroll
      for (int kk = 0; kk < 4; ++kk) {
        bf16x8 a = *(const bf16x8*)&sHb[p][rA][kk * 32 + kg * 8];
        axh = mfma16(a, wsm[kk], axh);
      }
#pragma unroll
      for (int i = 0; i < 4; ++i) {
        xh[i] = axh[i] + bhist;
        float xc = mr[i] * xr[i] + (1.f - mr[i]) * xh[i];
        sXcb[kg * 4 + i][colw] = f2bf(xc);
      }
    } else {
      f32x4 aal = {0.f, 0.f, 0.f, 0.f};
      aal = mfma16(gx[0], wsm[0], aal);
      aal = mfma16(gx[1], wsm[1], aal);
      aal = mfma16(mfrag[0], wsm[2], aal);
      aal = mfma16(mfrag[1], wsm[3], aal);
#pragma unroll
      for (int i = 0; i < 4; ++i) sAl[kg * 4 + i][colw] = sigm(aal[i] + bcomb);
#pragma unroll
      for (int i = 0; i < 4; ++i) xh[i] = 0.f;
    }
    __syncthreads();   // barrier 1: sXcb, sAl ready

    // ---- phase C ----
    // issue next-step m / x loads
    const float* mb = masks + (size_t)(b0 + rA) * 4096 + tn * 64 + kg * 8;
    f32x4 m0a = *(const f32x4*)mb,        m0b = *(const f32x4*)(mb + 4);
    f32x4 m1a = *(const f32x4*)(mb + 32), m1b = *(const f32x4*)(mb + 36);
    float xrn[4], mrn[4];
    if (w < 4) {
#pragma unroll
      for (int i = 0; i < 4; ++i) {
        size_t a = (size_t)(b0 + kg * 4 + i) * 4096 + tn * 64 + colw;
        xrn[i] = values[a];
        mrn[i] = masks[a];
      }
      f32x4 azh = {0.f, 0.f, 0.f, 0.f};
#pragma unroll
      for (int kk = 0; kk < 2; ++kk) {
        bf16x8 a = *(const bf16x8*)&sXcb[rA][kk * 32 + kg * 8];
        azh = mfma16(a, wfeat[kk], azh);
      }
      float n1 = 0.f, n2 = 0.f, n3 = 0.f, den = 0.f;
#pragma unroll
      for (int i = 0; i < 4; ++i) {
        int row = kg * 4 + i;
        float zh = azh[i] + bfeat;
        float al = sAl[row][colw];
        float ch = al * zh + (1.f - al) * xh[i];
        float cc = mr[i] * xr[i] + (1.f - mr[i]) * ch;
        size_t go = (size_t)(b0 + row) * 4096 + t * 64 + colw;
        out_est[go] = ch;
        out_imp[go] = cc;
        sCcb[row][colw] = f2bf(cc);
        n1 += fabsf(xh[i] - xr[i]) * mr[i];
        n2 += fabsf(zh - xr[i]) * mr[i];
        n3 += fabsf(ch - xr[i]) * mr[i];
        den += mr[i];
      }
#pragma unroll
      for (int off = 32; off > 0; off >>= 1) {
        n1 += __shfl_down(n1, off);
        n2 += __shfl_down(n2, off);
        n3 += __shfl_down(n3, off);
        den += __shfl_down(den, off);
      }
      if (l == 0) { sLoss[w][0] = n1; sLoss[w][1] = n2; sLoss[w][2] = n3; sLoss[w][3] = den; }
    } else {
#pragma unroll
      for (int i = 0; i < 4; ++i) { xrn[i] = 0.f; mrn[i] = 0.f; }
    }
    __syncthreads();   // barrier 2: sCcb, sLoss ready

    // ---- phase E: gates + LSTM + decay(t+1) ----
    if (tid < 4) {
      float s = sLoss[0][tid] + sLoss[1][tid] + sLoss[2][tid] + sLoss[3][tid];
      loss_ws[((size_t)t * 256 + wg) * 4 + tid] = s;
    }
    {
      f32x4 acc[4];
#pragma unroll
      for (int g = 0; g < 4; ++g) { f32x4 z = {0.f, 0.f, 0.f, 0.f}; acc[g] = z; }
#pragma unroll
      for (int kk = 0; kk < 8; ++kk) {
        bf16x8 a;
        if (kk < 2)      a = *(const bf16x8*)&sCcb[rA][kk * 32 + kg * 8];
        else if (kk < 4) a = mfrag[kk - 2];
        else             a = *(const bf16x8*)&sHb[p][rA][(kk - 4) * 32 + kg * 8];
#pragma unroll
        for (int g = 0; g < 4; ++g) acc[g] = mfma16(a, wgf[g][kk], acc[g]);
      }
#pragma unroll
      for (int i = 0; i < 4; ++i) {
        float ii = sigm(acc[0][i] + bg[0]);
        float ff = sigm(acc[1][i] + bg[1]);
        float g_ = tanh_fast(acc[2][i] + bg[2]);
        float oo = sigm(acc[3][i] + bg[3]);
        float c_ = ff * c_reg[i] + ii * g_;
        c_reg[i] = c_;
        h_reg[i] = oo * tanh_fast(c_);
      }
    }
    if (t == NT - 1) {
#pragma unroll
      for (int i = 0; i < 4; ++i) out_h[(size_t)(b0 + kg * 4 + i) * 128 + colh] = h_reg[i];
    } else {
      // convert next-step fragments; compute gamma_h(t+1); decay h; write sHb[p^1]
      dfrag[0] = cvt8(d0a, d0b);
      dfrag[1] = cvt8(d1a, d1b);
      if (w >= 4) {
        f32x4 wx0 = *(const f32x4*)&sWdxB[kg * 8],      wx0b = *(const f32x4*)&sWdxB[kg * 8 + 4];
        f32x4 bx0 = *(const f32x4*)&sWdxB[64 + kg * 8], bx0b = *(const f32x4*)&sWdxB[64 + kg * 8 + 4];
        f32x4 wx1 = *(const f32x4*)&sWdxB[32 + kg * 8],      wx1b = *(const f32x4*)&sWdxB[32 + kg * 8 + 4];
        f32x4 bx1 = *(const f32x4*)&sWdxB[96 + kg * 8], bx1b = *(const f32x4*)&sWdxB[96 + kg * 8 + 4];
        U8 u0, u1;
#pragma unroll
        for (int j = 0; j < 4; ++j) {
          u0.s[j]     = f2bf(__expf(-fmaxf(d0a[j] * wx0[j]  + bx0[j], 0.f)));
          u0.s[4 + j] = f2bf(__expf(-fmaxf(d0b[j] * wx0b[j] + bx0b[j], 0.f)));
          u1.s[j]     = f2bf(__expf(-fmaxf(d1a[j] * wx1[j]  + bx1[j], 0.f)));
          u1.s[4 + j] = f2bf(__expf(-fmaxf(d1b[j] * wx1b[j] + bx1b[j], 0.f)));
        }
        gx[0] = __builtin_bit_cast(bf16x8, u0);
        gx[1] = __builtin_bit_cast(bf16x8, u1);
      }
      f32x4 ga = {0.f, 0.f, 0.f, 0.f};
      ga = mfma16(dfrag[0], wdhf[0], ga);
      ga = mfma16(dfrag[1], wdhf[1], ga);
#pragma unroll
      for (int i = 0; i < 4; ++i) {
        float g = __expf(-fmaxf(ga[i] + bdh, 0.f));
        h_reg[i] *= g;
        sHb[p ^ 1][kg * 4 + i][colh] = f2bf(h_reg[i]);
      }
      mfrag[0] = cvt8(m0a, m0b);
      mfrag[1] = cvt8(m1a, m1b);
      if (w < 4) {
#pragma unroll
        for (int i = 0; i < 4; ++i) { xr[i] = xrn[i]; mr[i] = mrn[i]; }
      }
    }
    __syncthreads();   // barrier 3: sHb[p^1] ready for next step
  }
}

__global__ void rits_loss_kernel(const float* __restrict__ ws, float* __restrict__ out_loss) {
  int tid = threadIdx.x;  // 64 threads = 1 wave
  float n1 = 0.f, n2 = 0.f, n3 = 0.f, den = 0.f;
  for (int g = 0; g < 256; ++g) {
    const float* p = &ws[((size_t)tid * 256 + g) * 4];
    n1 += p[0]; n2 += p[1]; n3 += p[2]; den += p[3];
  }
  float lt = (n1 + n2 + n3) / (den + 1e-12f);
#pragma unroll
  for (int off = 32; off > 0; off >>= 1) lt += __shfl_down(lt, off);
  if (tid == 0) out_loss[0] = lt / 192.f;   // / (T * 3)
}

extern "C" void kernel_launch(void* const* d_in, const int* in_sizes, int n_in,
                              void* d_out, int out_size, void* d_ws, size_t ws_size,
                              hipStream_t stream) {
  const float* values = (const float*)d_in[0];
  const float* masks  = (const float*)d_in[1];
  const float* deltas = (const float*)d_in[2];
  const float* W_dh   = (const float*)d_in[3];
  const float* b_dh   = (const float*)d_in[4];
  const float* W_dx   = (const float*)d_in[5];
  const float* b_dx   = (const float*)d_in[6];
  const float* W_hist = (const float*)d_in[7];
  const float* b_hist = (const float*)d_in[8];
  const float* W_feat = (const float*)d_in[9];
  const float* b_feat = (const float*)d_in[10];
  const float* W_comb = (const float*)d_in[11];
  const float* b_comb = (const float*)d_in[12];
  const float* W_ih   = (const float*)d_in[13];
  const float* b_ih   = (const float*)d_in[14];
  const float* W_hh   = (const float*)d_in[15];
  const float* b_hh   = (const float*)d_in[16];

  float* out = (float*)d_out;
  float* out_imp = out;                       // [B,T,F]
  float* out_est = out + (size_t)BTF;         // [B,T,F]
  float* out_h   = out + (size_t)2 * BTF;     // [B,H]
  float* out_ls  = out + (size_t)2 * BTF + (size_t)NB * 128;  // scalar
  float* loss_ws = (float*)d_ws;              // [T][256 wg][4]

  rits_main_kernel<<<256, 512, 0, stream>>>(
      values, masks, deltas, W_dh, b_dh, W_dx, b_dx, W_hist, b_hist,
      W_feat, b_feat, W_comb, b_comb, W_ih, b_ih, W_hh, b_hh,
      out_imp, out_est, out_h, loss_ws);
  rits_loss_kernel<<<1, 64, 0, stream>>>(loss_ws, out_ls);
}

// Round 3
// 415.148 us; speedup vs baseline: 1.9605x; 1.9605x over previous
//
#include <hip/hip_runtime.h>

typedef float f32x4 __attribute__((ext_vector_type(4)));
typedef unsigned int u32x2 __attribute__((ext_vector_type(2)));
typedef __bf16 bf16x8 __attribute__((ext_vector_type(8)));

struct U8 { unsigned short s[8]; };
static_assert(sizeof(bf16x8) == 16, "bf16x8 must be 16B");

#define NB 4096
#define NT 64
#define BTF (NB * NT * 64)   // 16777216

__device__ __forceinline__ unsigned short f2bf(float x) {
  unsigned int u = __builtin_bit_cast(unsigned int, x);
  u += 0x7fffu + ((u >> 16) & 1u);       // round-to-nearest-even
  return (unsigned short)(u >> 16);
}

__device__ __forceinline__ f32x4 mfma16(bf16x8 a, bf16x8 b, f32x4 c) {
  return __builtin_amdgcn_mfma_f32_16x16x32_bf16(a, b, c, 0, 0, 0);
}

__device__ __forceinline__ bf16x8 cvt8(f32x4 a, f32x4 b) {
  U8 u;
#pragma unroll
  for (int j = 0; j < 4; ++j) { u.s[j] = f2bf(a[j]); u.s[4 + j] = f2bf(b[j]); }
  return __builtin_bit_cast(bf16x8, u);
}

__device__ __forceinline__ bf16x8 loadW8(const float* __restrict__ row, int k0) {
  f32x4 a = *(const f32x4*)(row + k0);
  f32x4 b = *(const f32x4*)(row + k0 + 4);
  return cvt8(a, b);
}

__device__ __forceinline__ bf16x8 loadW8zd(const float* __restrict__ row, int k0, int col) {
  f32x4 a = *(const f32x4*)(row + k0);
  f32x4 b = *(const f32x4*)(row + k0 + 4);
  U8 u;
#pragma unroll
  for (int j = 0; j < 4; ++j) {
    u.s[j]     = (k0 + j     == col) ? (unsigned short)0 : f2bf(a[j]);
    u.s[4 + j] = (k0 + 4 + j == col) ? (unsigned short)0 : f2bf(b[j]);
  }
  return __builtin_bit_cast(bf16x8, u);
}

__device__ __forceinline__ float sigm(float x) { return 1.f / (1.f + __expf(-x)); }
__device__ __forceinline__ float tanh_fast(float x) { return 1.f - 2.f / (__expf(2.f * x) + 1.f); }

__global__ __launch_bounds__(512, 2) void rits_main_kernel(
    const float* __restrict__ values, const float* __restrict__ masks,
    const float* __restrict__ deltas,
    const float* __restrict__ W_dh, const float* __restrict__ b_dh,
    const float* __restrict__ W_dx, const float* __restrict__ b_dx,
    const float* __restrict__ W_hist, const float* __restrict__ b_hist,
    const float* __restrict__ W_feat, const float* __restrict__ b_feat,
    const float* __restrict__ W_comb, const float* __restrict__ b_comb,
    const float* __restrict__ W_ih, const float* __restrict__ b_ih,
    const float* __restrict__ W_hh, const float* __restrict__ b_hh,
    float* __restrict__ out_imp, float* __restrict__ out_est,
    float* __restrict__ out_h, float* __restrict__ loss_ws) {
  const int tid = threadIdx.x;
  const int w = tid >> 6;          // wave 0..7
  const int l = tid & 63;          // lane
  const int rA = l & 15;           // MFMA A-row / C-col index
  const int kg = l >> 4;           // k-group 0..3
  const int wg = blockIdx.x;
  const int b0 = wg * 16;
  const int colh = w * 16 + rA;          // 0..127
  const int colw = (w & 3) * 16 + rA;    // 0..63
  const int s = tid & 255;               // staging index for w>=4
  const int sr = s >> 4, sq = s & 15;

  // double-buffered staged activations (f32 + bf16 frag tiles for m,d)
  __shared__ float sX[2][16][68], sM[2][16][68], sD[2][16][68];
  __shared__ unsigned short sMb[2][16][72], sDb[2][16][72];
  __shared__ unsigned short sHb[16][136];      // decayed h, bf16
  __shared__ unsigned short sXcb[16][72], sCcb[16][72];
  __shared__ float sAl[16][68];
  __shared__ float sLoss[4][4];

  // ---------------- weights -> registers ----------------
  bf16x8 wgf[4][8];
#pragma unroll
  for (int g = 0; g < 4; ++g) {
    int col = g * 128 + colh;
#pragma unroll
    for (int kk = 0; kk < 4; ++kk) wgf[g][kk] = loadW8(W_ih + (size_t)col * 128, kk * 32 + kg * 8);
#pragma unroll
    for (int kk = 0; kk < 4; ++kk) wgf[g][4 + kk] = loadW8(W_hh + (size_t)col * 128, kk * 32 + kg * 8);
  }
  bf16x8 wdhf[2];
#pragma unroll
  for (int kk = 0; kk < 2; ++kk) wdhf[kk] = loadW8(W_dh + (size_t)colh * 64, kk * 32 + kg * 8);

  bf16x8 wsm[4], wfeat[2];
  float wx0[8], bx0[8], wx1[8], bx1[8];
#pragma unroll
  for (int j = 0; j < 8; ++j) { wx0[j] = 0.f; bx0[j] = 0.f; wx1[j] = 0.f; bx1[j] = 0.f; }
  if (w < 4) {
#pragma unroll
    for (int kk = 0; kk < 4; ++kk) wsm[kk] = loadW8(W_hist + (size_t)colw * 128, kk * 32 + kg * 8);
#pragma unroll
    for (int kk = 0; kk < 2; ++kk) wfeat[kk] = loadW8zd(W_feat + (size_t)colw * 64, kk * 32 + kg * 8, colw);
  } else {
#pragma unroll
    for (int kk = 0; kk < 4; ++kk) wsm[kk] = loadW8(W_comb + (size_t)colw * 128, kk * 32 + kg * 8);
#pragma unroll
    for (int kk = 0; kk < 2; ++kk) { U8 z = {}; wfeat[kk] = __builtin_bit_cast(bf16x8, z); }
#pragma unroll
    for (int j = 0; j < 8; ++j) {
      int f0 = kg * 8 + j, f1 = 32 + kg * 8 + j;
      wx0[j] = W_dx[f0 * 65]; bx0[j] = b_dx[f0];
      wx1[j] = W_dx[f1 * 65]; bx1[j] = b_dx[f1];
    }
  }

  const float bdh = b_dh[colh];
  const float bhist = (w < 4) ? b_hist[colw] : 0.f;
  const float bfeat = (w < 4) ? b_feat[colw] : 0.f;
  const float bcomb = (w >= 4) ? b_comb[colw] : 0.f;
  float bg[4];
#pragma unroll
  for (int g = 0; g < 4; ++g) bg[g] = b_ih[g * 128 + colh] + b_hh[g * 128 + colh];

  f32x4 h_reg = {0.f, 0.f, 0.f, 0.f};
  f32x4 c_reg = {0.f, 0.f, 0.f, 0.f};

  // ---------------- prologue: stage t=0 into buf 0 ----------------
  if (w >= 4) {
    size_t ga = (size_t)(b0 + sr) * 4096 + sq * 4;
    f32x4 vx = *(const f32x4*)&values[ga];
    f32x4 vm = *(const f32x4*)&masks[ga];
    f32x4 vd = *(const f32x4*)&deltas[ga];
    *(f32x4*)&sX[0][sr][sq * 4] = vx;
    *(f32x4*)&sM[0][sr][sq * 4] = vm;
    *(f32x4*)&sD[0][sr][sq * 4] = vd;
    u32x2 pm, pd;
    pm[0] = (unsigned int)f2bf(vm[0]) | ((unsigned int)f2bf(vm[1]) << 16);
    pm[1] = (unsigned int)f2bf(vm[2]) | ((unsigned int)f2bf(vm[3]) << 16);
    pd[0] = (unsigned int)f2bf(vd[0]) | ((unsigned int)f2bf(vd[1]) << 16);
    pd[1] = (unsigned int)f2bf(vd[2]) | ((unsigned int)f2bf(vd[3]) << 16);
    *(u32x2*)&sMb[0][sr][sq * 4] = pm;
    *(u32x2*)&sDb[0][sr][sq * 4] = pd;
  }
  __syncthreads();

  // ---------------- time loop: 4 barriers per step ----------------
  for (int t = 0; t < NT; ++t) {
    const int p = t & 1;
    const int tn = (t + 1 < NT) ? (t + 1) : (NT - 1);

    // ---- P1: issue t+1 staging loads; decay h (all); gamma_x (w>=4) ----
    f32x4 vx, vm, vd;
    if (w >= 4) {
      size_t ga = (size_t)(b0 + sr) * 4096 + (size_t)tn * 64 + sq * 4;
      vx = *(const f32x4*)&values[ga];
      vm = *(const f32x4*)&masks[ga];
      vd = *(const f32x4*)&deltas[ga];
    }
    {
      bf16x8 a0 = *(const bf16x8*)&sDb[p][rA][kg * 8];
      bf16x8 a1 = *(const bf16x8*)&sDb[p][rA][32 + kg * 8];
      f32x4 ga4 = {0.f, 0.f, 0.f, 0.f};
      ga4 = mfma16(a0, wdhf[0], ga4);
      ga4 = mfma16(a1, wdhf[1], ga4);
#pragma unroll
      for (int i = 0; i < 4; ++i) {
        float g = __expf(-fmaxf(ga4[i] + bdh, 0.f));
        h_reg[i] *= g;
        sHb[kg * 4 + i][colh] = f2bf(h_reg[i]);
      }
    }
    bf16x8 gx0, gx1;
    if (w >= 4) {
      f32x4 dA = *(const f32x4*)&sD[p][rA][kg * 8];
      f32x4 dB = *(const f32x4*)&sD[p][rA][kg * 8 + 4];
      f32x4 dC = *(const f32x4*)&sD[p][rA][32 + kg * 8];
      f32x4 dD = *(const f32x4*)&sD[p][rA][32 + kg * 8 + 4];
      U8 u0, u1;
#pragma unroll
      for (int j = 0; j < 4; ++j) {
        u0.s[j]     = f2bf(__expf(-fmaxf(dA[j] * wx0[j]     + bx0[j],     0.f)));
        u0.s[4 + j] = f2bf(__expf(-fmaxf(dB[j] * wx0[4 + j] + bx0[4 + j], 0.f)));
        u1.s[j]     = f2bf(__expf(-fmaxf(dC[j] * wx1[j]     + bx1[j],     0.f)));
        u1.s[4 + j] = f2bf(__expf(-fmaxf(dD[j] * wx1[4 + j] + bx1[4 + j], 0.f)));
      }
      gx0 = __builtin_bit_cast(bf16x8, u0);
      gx1 = __builtin_bit_cast(bf16x8, u1);
    } else {
      U8 z = {};
      gx0 = gx1 = __builtin_bit_cast(bf16x8, z);
    }
    __syncthreads();   // bar1: sHb ready

    // ---- P2: w<4: x_h GEMM + x_c; w>=4: alpha GEMM ----
    float xh[4], xr[4], mr[4];
    if (w < 4) {
      f32x4 axh = {0.f, 0.f, 0.f, 0.f};
#pragma unroll
      for (int kk = 0; kk < 4; ++kk) {
        bf16x8 a = *(const bf16x8*)&sHb[rA][kk * 32 + kg * 8];
        axh = mfma16(a, wsm[kk], axh);
      }
#pragma unroll
      for (int i = 0; i < 4; ++i) {
        int row = kg * 4 + i;
        xr[i] = sX[p][row][colw];
        mr[i] = sM[p][row][colw];
        xh[i] = axh[i] + bhist;
        float xc = mr[i] * xr[i] + (1.f - mr[i]) * xh[i];
        sXcb[row][colw] = f2bf(xc);
      }
    } else {
      f32x4 aal = {0.f, 0.f, 0.f, 0.f};
      aal = mfma16(gx0, wsm[0], aal);
      aal = mfma16(gx1, wsm[1], aal);
      bf16x8 a2 = *(const bf16x8*)&sMb[p][rA][kg * 8];
      bf16x8 a3 = *(const bf16x8*)&sMb[p][rA][32 + kg * 8];
      aal = mfma16(a2, wsm[2], aal);
      aal = mfma16(a3, wsm[3], aal);
#pragma unroll
      for (int i = 0; i < 4; ++i) sAl[kg * 4 + i][colw] = sigm(aal[i] + bcomb);
#pragma unroll
      for (int i = 0; i < 4; ++i) { xh[i] = 0.f; xr[i] = 0.f; mr[i] = 0.f; }
    }
    __syncthreads();   // bar2: sXcb, sAl ready

    // ---- P3: w<4: z_h GEMM + outputs + loss; w>=4: write staged t+1 ----
    if (w < 4) {
      f32x4 azh = {0.f, 0.f, 0.f, 0.f};
#pragma unroll
      for (int kk = 0; kk < 2; ++kk) {
        bf16x8 a = *(const bf16x8*)&sXcb[rA][kk * 32 + kg * 8];
        azh = mfma16(a, wfeat[kk], azh);
      }
      float n1 = 0.f, n2 = 0.f, n3 = 0.f, den = 0.f;
#pragma unroll
      for (int i = 0; i < 4; ++i) {
        int row = kg * 4 + i;
        float zh = azh[i] + bfeat;
        float al = sAl[row][colw];
        float ch = al * zh + (1.f - al) * xh[i];
        float cc = mr[i] * xr[i] + (1.f - mr[i]) * ch;
        size_t go = (size_t)(b0 + row) * 4096 + (size_t)t * 64 + colw;
        out_est[go] = ch;
        out_imp[go] = cc;
        sCcb[row][colw] = f2bf(cc);
        n1 += fabsf(xh[i] - xr[i]) * mr[i];
        n2 += fabsf(zh - xr[i]) * mr[i];
        n3 += fabsf(ch - xr[i]) * mr[i];
        den += mr[i];
      }
#pragma unroll
      for (int off = 32; off > 0; off >>= 1) {
        n1 += __shfl_down(n1, off);
        n2 += __shfl_down(n2, off);
        n3 += __shfl_down(n3, off);
        den += __shfl_down(den, off);
      }
      if (l == 0) { sLoss[w][0] = n1; sLoss[w][1] = n2; sLoss[w][2] = n3; sLoss[w][3] = den; }
    } else {
      *(f32x4*)&sX[p ^ 1][sr][sq * 4] = vx;
      *(f32x4*)&sM[p ^ 1][sr][sq * 4] = vm;
      *(f32x4*)&sD[p ^ 1][sr][sq * 4] = vd;
      u32x2 pm, pd;
      pm[0] = (unsigned int)f2bf(vm[0]) | ((unsigned int)f2bf(vm[1]) << 16);
      pm[1] = (unsigned int)f2bf(vm[2]) | ((unsigned int)f2bf(vm[3]) << 16);
      pd[0] = (unsigned int)f2bf(vd[0]) | ((unsigned int)f2bf(vd[1]) << 16);
      pd[1] = (unsigned int)f2bf(vd[2]) | ((unsigned int)f2bf(vd[3]) << 16);
      *(u32x2*)&sMb[p ^ 1][sr][sq * 4] = pm;
      *(u32x2*)&sDb[p ^ 1][sr][sq * 4] = pd;
    }
    __syncthreads();   // bar3: sCcb, sLoss, staged t+1 ready

    // ---- E: gate GEMM + LSTM (registers) ----
    if (tid < 4) {
      float ls = sLoss[0][tid] + sLoss[1][tid] + sLoss[2][tid] + sLoss[3][tid];
      loss_ws[((size_t)t * 256 + wg) * 4 + tid] = ls;
    }
    {
      f32x4 acc[4];
#pragma unroll
      for (int g = 0; g < 4; ++g) { f32x4 z = {0.f, 0.f, 0.f, 0.f}; acc[g] = z; }
#pragma unroll
      for (int kk = 0; kk < 8; ++kk) {
        bf16x8 a;
        if (kk < 2)      a = *(const bf16x8*)&sCcb[rA][kk * 32 + kg * 8];
        else if (kk < 4) a = *(const bf16x8*)&sMb[p][rA][(kk - 2) * 32 + kg * 8];
        else             a = *(const bf16x8*)&sHb[rA][(kk - 4) * 32 + kg * 8];
#pragma unroll
        for (int g = 0; g < 4; ++g) acc[g] = mfma16(a, wgf[g][kk], acc[g]);
      }
#pragma unroll
      for (int i = 0; i < 4; ++i) {
        float ii = sigm(acc[0][i] + bg[0]);
        float ff = sigm(acc[1][i] + bg[1]);
        float g_ = tanh_fast(acc[2][i] + bg[2]);
        float oo = sigm(acc[3][i] + bg[3]);
        float c_ = ff * c_reg[i] + ii * g_;
        c_reg[i] = c_;
        h_reg[i] = oo * tanh_fast(c_);
      }
    }
    if (t == NT - 1) {
#pragma unroll
      for (int i = 0; i < 4; ++i) out_h[(size_t)(b0 + kg * 4 + i) * 128 + colh] = h_reg[i];
    }
    __syncthreads();   // bar4: sHb/sMb/sCcb reads done before t+1 overwrites
  }
}

__global__ void rits_loss_kernel(const float* __restrict__ ws, float* __restrict__ out_loss) {
  int tid = threadIdx.x;  // 64 threads = 1 wave
  float n1 = 0.f, n2 = 0.f, n3 = 0.f, den = 0.f;
  for (int g = 0; g < 256; ++g) {
    const float* p = &ws[((size_t)tid * 256 + g) * 4];
    n1 += p[0]; n2 += p[1]; n3 += p[2]; den += p[3];
  }
  float lt = (n1 + n2 + n3) / (den + 1e-12f);
#pragma unroll
  for (int off = 32; off > 0; off >>= 1) lt += __shfl_down(lt, off);
  if (tid == 0) out_loss[0] = lt / 192.f;   // / (T * 3)
}

extern "C" void kernel_launch(void* const* d_in, const int* in_sizes, int n_in,
                              void* d_out, int out_size, void* d_ws, size_t ws_size,
                              hipStream_t stream) {
  const float* values = (const float*)d_in[0];
  const float* masks  = (const float*)d_in[1];
  const float* deltas = (const float*)d_in[2];
  const float* W_dh   = (const float*)d_in[3];
  const float* b_dh   = (const float*)d_in[4];
  const float* W_dx   = (const float*)d_in[5];
  const float* b_dx   = (const float*)d_in[6];
  const float* W_hist = (const float*)d_in[7];
  const float* b_hist = (const float*)d_in[8];
  const float* W_feat = (const float*)d_in[9];
  const float* b_feat = (const float*)d_in[10];
  const float* W_comb = (const float*)d_in[11];
  const float* b_comb = (const float*)d_in[12];
  const float* W_ih   = (const float*)d_in[13];
  const float* b_ih   = (const float*)d_in[14];
  const float* W_hh   = (const float*)d_in[15];
  const float* b_hh   = (const float*)d_in[16];

  float* out = (float*)d_out;
  float* out_imp = out;                       // [B,T,F]
  float* out_est = out + (size_t)BTF;         // [B,T,F]
  float* out_h   = out + (size_t)2 * BTF;     // [B,H]
  float* out_ls  = out + (size_t)2 * BTF + (size_t)NB * 128;  // scalar
  float* loss_ws = (float*)d_ws;              // [T][256 wg][4]

  rits_main_kernel<<<256, 512, 0, stream>>>(
      values, masks, deltas, W_dh, b_dh, W_dx, b_dx, W_hist, b_hist,
      W_feat, b_feat, W_comb, b_comb, W_ih, b_ih, W_hh, b_hh,
      out_imp, out_est, out_h, loss_ws);
  rits_loss_kernel<<<1, 64, 0, stream>>>(loss_ws, out_ls);
}